// Round 9
// baseline (11801.054 us; speedup 1.0000x reference)
//
#include <hip/hip_runtime.h>
#include <math.h>

// 4-layer tanh RNN (H=2048, T=512) + FC on last timestep.
// Round-9: DEPTH-4 SCAFFOLD x EXACT R2 CORE (the never-tested cell).
//  - Evidence: r2 core (16 rows/blk, fp32 wgts, LDS exchange, combined
//    sentinel poll, sleep(2), 2 barriers) = 6.2us all-to-all cadence.
//    r4-core variants (32 rows, f16 fdot2, halving reduce, direct-reg) =
//    ~17us cadence under EVERY handshake mechanism tried (r4-r8).
//    Conclusion: bisect the CORE, not the handshake. This round keeps the
//    r2 core byte-for-byte and only changes the scaffold to depth-4.
//  - 512 blocks x 512 threads, 2 blocks/CU (__launch_bounds__(512,4) caps
//    VGPR at 128 >= r2's measured 104; LDS 2x16.9KB = 34KB/CU ok).
//    layer = blk>>7, gb = blk&127, 128 blocks/layer, 16 rows/block.
//  - Critical path ~T+3 = 515 handshakes (vs r2's 1024).
//  - Benign failure: if 2/CU co-residency fails, execution degrades to
//    phased r2 behavior (~6.5ms), not deadlock (layer groups retire in
//    dependency order).

#define HH 2048
#define TT 512
#define NBLK 512
#define GRPB 128     // blocks per layer
#define NTH 512

typedef unsigned long long u64;
typedef unsigned int u32;

__device__ __forceinline__ u64 ld_a8(const float* p) {
  return __hip_atomic_load((const u64*)p, __ATOMIC_RELAXED,
                           __HIP_MEMORY_SCOPE_AGENT);
}
__device__ __forceinline__ void st_a4(float* p, float v) {
  __hip_atomic_store(p, v, __ATOMIC_RELAXED, __HIP_MEMORY_SCOPE_AGENT);
}
__device__ __forceinline__ bool fresh8(u64 v) {
  return ((u32)v != 0xFFFFFFFFu) & ((u32)(v >> 32) != 0xFFFFFFFFu);
}

__launch_bounds__(NTH, 4)
__global__ void rnn_d4r2(const float* __restrict__ x,
                         const float* __restrict__ w_ih,
                         const float* __restrict__ w_hh,
                         const float* __restrict__ b_ih,
                         const float* __restrict__ b_hh,
                         const float* __restrict__ w_fc,
                         const float* __restrict__ b_fc,
                         float* __restrict__ out,
                         float* ws)
{
  const int blk  = blockIdx.x;
  const int l    = blk >> 7;           // layer 0..3
  const int gb   = blk & (GRPB - 1);   // block within layer
  const int tid  = threadIdx.x;
  const int wid  = tid >> 6;
  const int lane = tid & 63;
  const int band = wid >> 1;           // 4 bands of 4 rows
  const int half = wid & 1;            // column half
  const int rowbase = gb * 16 + band * 4;

  float* outB      = ws + (size_t)l * (TT + 1) * HH;
  const float* inB = ws + (size_t)(l - 1) * (TT + 1) * HH;  // l>0 only

  __shared__ float hex_own[HH];    // h_{t-1}, own layer
  __shared__ float hex_prev[HH];   // h_t, previous layer
  __shared__ float partial[8][4];

  // cooperative poll slice: wave w owns cols [w*256, w*256+256); 4 floats/lane
  const int sl = wid * 256 + lane * 4;

  // ---- weights into VGPRs: lane owns cols c(k)=half*1024+128k+2*lane ----
  float wih[4][16], whh[4][16];
#pragma unroll
  for (int r = 0; r < 4; ++r) {
    const float* pih = w_ih + ((size_t)l * HH + rowbase + r) * HH;
    const float* phh = w_hh + ((size_t)l * HH + rowbase + r) * HH;
#pragma unroll
    for (int k = 0; k < 8; ++k) {
      int c = half * 1024 + k * 128 + lane * 2;
      float2 a = *(const float2*)(pih + c);
      float2 b = *(const float2*)(phh + c);
      wih[r][2 * k] = a.x; wih[r][2 * k + 1] = a.y;
      whh[r][2 * k] = b.x; whh[r][2 * k + 1] = b.y;
    }
  }
  float fbias = 0.f;
  if (tid < 16)
    fbias = b_ih[l * HH + gb * 16 + tid] + b_hh[l * HH + gb * 16 + tid];

  for (int t = 0; t < TT; ++t) {
    // ---- cooperative sentinel poll + fetch (own slot t, prev slot t+1) ---
    const float* po = outB + (size_t)t * HH + sl;
    const float* pp = (l > 0) ? (inB + (size_t)(t + 1) * HH + sl)
                              : (const float*)0;
    u64 o0, o1, p0 = 0, p1 = 0;
    for (;;) {
      o0 = ld_a8(po);
      o1 = ld_a8(po + 2);
      if (l > 0) { p0 = ld_a8(pp); p1 = ld_a8(pp + 2); }
      bool ok = fresh8(o0) & fresh8(o1);
      if (l > 0) ok = ok & fresh8(p0) & fresh8(p1);
      if (__all(ok)) break;
      __builtin_amdgcn_s_sleep(2);
    }
    *(u64*)(hex_own + sl)     = o0;
    *(u64*)(hex_own + sl + 2) = o1;
    if (l > 0) {
      *(u64*)(hex_prev + sl)     = p0;
      *(u64*)(hex_prev + sl + 2) = p1;
    }
    __syncthreads();   // barrier1: hexch ready

    float hh[16], hi[16];
#pragma unroll
    for (int k = 0; k < 8; ++k) {
      int c = half * 1024 + k * 128 + lane * 2;
      float2 v = *(const float2*)(hex_own + c);
      hh[2 * k] = v.x; hh[2 * k + 1] = v.y;
    }
    if (l == 0) {
#pragma unroll
      for (int k = 0; k < 8; ++k) {
        int c = half * 1024 + k * 128 + lane * 2;
        hi[2 * k]     = x[(size_t)c * TT + t];
        hi[2 * k + 1] = x[(size_t)(c + 1) * TT + t];
      }
    } else {
#pragma unroll
      for (int k = 0; k < 8; ++k) {
        int c = half * 1024 + k * 128 + lane * 2;
        float2 v = *(const float2*)(hex_prev + c);
        hi[2 * k] = v.x; hi[2 * k + 1] = v.y;
      }
    }

    float a0 = 0.f, a1 = 0.f, a2 = 0.f, a3 = 0.f;
#pragma unroll
    for (int k = 0; k < 16; ++k) {
      a0 += whh[0][k] * hh[k]; a0 += wih[0][k] * hi[k];
      a1 += whh[1][k] * hh[k]; a1 += wih[1][k] * hi[k];
      a2 += whh[2][k] * hh[k]; a2 += wih[2][k] * hi[k];
      a3 += whh[3][k] * hh[k]; a3 += wih[3][k] * hi[k];
    }
#pragma unroll
    for (int m = 1; m < 64; m <<= 1) {
      a0 += __shfl_xor(a0, m, 64);
      a1 += __shfl_xor(a1, m, 64);
      a2 += __shfl_xor(a2, m, 64);
      a3 += __shfl_xor(a3, m, 64);
    }
    if (lane == 0) {
      partial[wid][0] = a0; partial[wid][1] = a1;
      partial[wid][2] = a2; partial[wid][3] = a3;
    }
    __syncthreads();   // barrier2: partials ready
    if (tid < 16) {
      int bnd = tid >> 2, r = tid & 3;
      float s = partial[bnd * 2][r] + partial[bnd * 2 + 1][r] + fbias;
      st_a4(outB + (size_t)(t + 1) * HH + gb * 16 + tid, tanhf(s));
    }
    // partial[] reuse at t+1 is gated by barrier1(t+1), which wave0 reaches
    // only after its finalize store above — exactly r2's proven ordering.
  }

  // ---- FC on h3[T-1]: layer-3 group (weight regs dead, reuse for w_fc) ----
  if (l == 3) {
    float wf[4][16];
#pragma unroll
    for (int r = 0; r < 4; ++r) {
      const float* pf = w_fc + (size_t)(rowbase + r) * HH;
#pragma unroll
      for (int k = 0; k < 8; ++k) {
        int c = half * 1024 + k * 128 + lane * 2;
        float2 a = *(const float2*)(pf + c);
        wf[r][2 * k] = a.x; wf[r][2 * k + 1] = a.y;
      }
    }
    const float* ph = outB + (size_t)TT * HH + sl;
    u64 o0, o1;
    for (;;) {
      o0 = ld_a8(ph);
      o1 = ld_a8(ph + 2);
      if (__all(fresh8(o0) & fresh8(o1))) break;
      __builtin_amdgcn_s_sleep(2);
    }
    *(u64*)(hex_own + sl)     = o0;
    *(u64*)(hex_own + sl + 2) = o1;
    __syncthreads();

    float hv[16];
#pragma unroll
    for (int k = 0; k < 8; ++k) {
      int c = half * 1024 + k * 128 + lane * 2;
      float2 v = *(const float2*)(hex_own + c);
      hv[2 * k] = v.x; hv[2 * k + 1] = v.y;
    }
    float a0 = 0.f, a1 = 0.f, a2 = 0.f, a3 = 0.f;
#pragma unroll
    for (int k = 0; k < 16; ++k) {
      a0 += wf[0][k] * hv[k];
      a1 += wf[1][k] * hv[k];
      a2 += wf[2][k] * hv[k];
      a3 += wf[3][k] * hv[k];
    }
#pragma unroll
    for (int m = 1; m < 64; m <<= 1) {
      a0 += __shfl_xor(a0, m, 64);
      a1 += __shfl_xor(a1, m, 64);
      a2 += __shfl_xor(a2, m, 64);
      a3 += __shfl_xor(a3, m, 64);
    }
    if (lane == 0) {
      partial[wid][0] = a0; partial[wid][1] = a1;
      partial[wid][2] = a2; partial[wid][3] = a3;
    }
    __syncthreads();
    if (tid < 16) {
      int row = gb * 16 + tid;
      int bnd = tid >> 2, r = tid & 3;
      out[row] = partial[bnd * 2][r] + partial[bnd * 2 + 1][r] + b_fc[row];
    }
  }
}

extern "C" void kernel_launch(void* const* d_in, const int* in_sizes, int n_in,
                              void* d_out, int out_size, void* d_ws, size_t ws_size,
                              hipStream_t stream) {
  const float* x    = (const float*)d_in[0];
  const float* w_ih = (const float*)d_in[1];
  const float* w_hh = (const float*)d_in[2];
  const float* b_ih = (const float*)d_in[3];
  const float* b_hh = (const float*)d_in[4];
  const float* w_fc = (const float*)d_in[5];
  const float* b_fc = (const float*)d_in[6];
  float* out = (float*)d_out;
  float* ws  = (float*)d_ws;

  // 4 exchange buffers (one per layer): (TT+1) x HH floats each.
  // Sentinel-fill, then zero slot 0 (= h_{-1}) of each.
  const size_t bufFloats = (size_t)(TT + 1) * HH;
  hipMemsetAsync(ws, 0xFF, 4 * bufFloats * sizeof(float), stream);
  for (int l = 0; l < 4; ++l)
    hipMemsetAsync(ws + l * bufFloats, 0, HH * sizeof(float), stream);

  rnn_d4r2<<<NBLK, NTH, 0, stream>>>(x, w_ih, w_hh, b_ih, b_hh,
                                     w_fc, b_fc, out, ws);
}

// Round 10
// 6382.586 us; speedup vs baseline: 1.8489x; 1.8489x over previous
//
#include <hip/hip_runtime.h>
#include <math.h>

// 4-layer tanh RNN (H=2048, T=512) + FC on last timestep.
// Round-10: depth-4 scaffold x r2 core, REGISTER BUDGET ENGINEERED TO FIT.
//  - r9 post-mortem: __launch_bounds__(512,4) = 128-reg unified cap; r2's
//    fp32 weights demand ~170 -> spill -> 15.6 GB scratch fetch (VGPR=64 in
//    counters). Same cliff as r3. Scaffold still untested.
//  - This round: ONE core change vs r2 — weights f16-packed consumed via
//    v_dot2_f32_f16 (accuracy proven in r4..r8, absmax 9.77e-4). Demand:
//    64 wgt + 16 packed operands + ~30 misc ~= 110 <= 128. No spill
//    (verify: VGPR_Count >= ~100, FETCH ~200 MB).
//  - Everything else r2-verbatim: 16 rows/block, 128 blocks/layer (512
//    blocks, 2/CU), cooperative combined sentinel poll (data-as-flag
//    0xFFFFFFFF, s_sleep(2)), LDS hexch exchange, barrier1 + barrier2,
//    4-accumulator 6-level shfl_xor reduce, tid<16 finalize (fp32 bias +
//    tanhf), relaxed agent stores.
//  - Critical path ~T+3 = 515 handshakes (vs r2's 1024 at 6.2us = 6.3ms).

#define HH 2048
#define TT 512
#define NBLK 512
#define GRPB 128     // blocks per layer
#define NTH 512

typedef unsigned long long u64;
typedef unsigned int u32;
typedef _Float16 h2 __attribute__((ext_vector_type(2)));

#if defined(__has_builtin)
#if __has_builtin(__builtin_amdgcn_fdot2)
#define HAS_FDOT2 1
#endif
#endif

__device__ __forceinline__ u64 ld_a8(const float* p) {
  return __hip_atomic_load((const u64*)p, __ATOMIC_RELAXED,
                           __HIP_MEMORY_SCOPE_AGENT);
}
__device__ __forceinline__ void st_a4(float* p, float v) {
  __hip_atomic_store(p, v, __ATOMIC_RELAXED, __HIP_MEMORY_SCOPE_AGENT);
}
__device__ __forceinline__ bool fresh8(u64 v) {
  return ((u32)v != 0xFFFFFFFFu) & ((u32)(v >> 32) != 0xFFFFFFFFu);
}
__device__ __forceinline__ h2 pk2(float a, float b) {
  h2 r; r[0] = (_Float16)a; r[1] = (_Float16)b; return r;   // RNE converts
}
__device__ __forceinline__ float dot2(h2 a, h2 b, float c) {
#ifdef HAS_FDOT2
  return __builtin_amdgcn_fdot2(a, b, c, false);
#else
  return c + (float)a[0] * (float)b[0] + (float)a[1] * (float)b[1];
#endif
}

__launch_bounds__(NTH, 4)
__global__ void rnn_d4h(const float* __restrict__ x,
                        const float* __restrict__ w_ih,
                        const float* __restrict__ w_hh,
                        const float* __restrict__ b_ih,
                        const float* __restrict__ b_hh,
                        const float* __restrict__ w_fc,
                        const float* __restrict__ b_fc,
                        float* __restrict__ out,
                        float* ws)
{
  const int blk  = blockIdx.x;
  const int l    = blk >> 7;           // layer 0..3
  const int gb   = blk & (GRPB - 1);   // block within layer
  const int tid  = threadIdx.x;
  const int wid  = tid >> 6;
  const int lane = tid & 63;
  const int band = wid >> 1;           // 4 bands of 4 rows
  const int half = wid & 1;            // column half
  const int rowbase = gb * 16 + band * 4;

  float* outB      = ws + (size_t)l * (TT + 1) * HH;
  const float* inB = ws + (size_t)(l - 1) * (TT + 1) * HH;  // l>0 only

  __shared__ float hex_own[HH];    // h_{t-1}, own layer
  __shared__ float hex_prev[HH];   // h_t, previous layer
  __shared__ float partial[8][4];

  // cooperative poll slice: wave w owns cols [w*256, w*256+256); 4 floats/lane
  const int sl = wid * 256 + lane * 4;

  // ---- weights into VGPRs, f16-packed: lane cols c(k)=half*1024+128k+2lane
  h2 wih[4][8], whh[4][8];
#pragma unroll
  for (int r = 0; r < 4; ++r) {
    const float* pih = w_ih + ((size_t)l * HH + rowbase + r) * HH;
    const float* phh = w_hh + ((size_t)l * HH + rowbase + r) * HH;
#pragma unroll
    for (int k = 0; k < 8; ++k) {
      int c = half * 1024 + k * 128 + lane * 2;
      float2 a = *(const float2*)(pih + c);
      float2 b = *(const float2*)(phh + c);
      wih[r][k] = pk2(a.x, a.y);
      whh[r][k] = pk2(b.x, b.y);
    }
  }
  float fbias = 0.f;
  if (tid < 16)
    fbias = b_ih[l * HH + gb * 16 + tid] + b_hh[l * HH + gb * 16 + tid];

  for (int t = 0; t < TT; ++t) {
    // ---- cooperative sentinel poll + fetch (own slot t, prev slot t+1) ---
    const float* po = outB + (size_t)t * HH + sl;
    const float* pp = (l > 0) ? (inB + (size_t)(t + 1) * HH + sl)
                              : (const float*)0;
    u64 o0, o1, p0 = 0, p1 = 0;
    for (;;) {
      o0 = ld_a8(po);
      o1 = ld_a8(po + 2);
      if (l > 0) { p0 = ld_a8(pp); p1 = ld_a8(pp + 2); }
      bool ok = fresh8(o0) & fresh8(o1);
      if (l > 0) ok = ok & fresh8(p0) & fresh8(p1);
      if (__all(ok)) break;
      __builtin_amdgcn_s_sleep(2);
    }
    *(u64*)(hex_own + sl)     = o0;
    *(u64*)(hex_own + sl + 2) = o1;
    if (l > 0) {
      *(u64*)(hex_prev + sl)     = p0;
      *(u64*)(hex_prev + sl + 2) = p1;
    }
    __syncthreads();   // barrier1: hexch ready

    // build packed operands straight from LDS (no float staging arrays)
    h2 ph[8], pi[8];
#pragma unroll
    for (int k = 0; k < 8; ++k) {
      int c = half * 1024 + k * 128 + lane * 2;
      float2 v = *(const float2*)(hex_own + c);
      ph[k] = pk2(v.x, v.y);
    }
    if (l == 0) {
#pragma unroll
      for (int k = 0; k < 8; ++k) {
        int c = half * 1024 + k * 128 + lane * 2;
        pi[k] = pk2(x[(size_t)c * TT + t], x[(size_t)(c + 1) * TT + t]);
      }
    } else {
#pragma unroll
      for (int k = 0; k < 8; ++k) {
        int c = half * 1024 + k * 128 + lane * 2;
        float2 v = *(const float2*)(hex_prev + c);
        pi[k] = pk2(v.x, v.y);
      }
    }

    float a0 = 0.f, a1 = 0.f, a2 = 0.f, a3 = 0.f;
#pragma unroll
    for (int k = 0; k < 8; ++k) {
      a0 = dot2(whh[0][k], ph[k], a0); a0 = dot2(wih[0][k], pi[k], a0);
      a1 = dot2(whh[1][k], ph[k], a1); a1 = dot2(wih[1][k], pi[k], a1);
      a2 = dot2(whh[2][k], ph[k], a2); a2 = dot2(wih[2][k], pi[k], a2);
      a3 = dot2(whh[3][k], ph[k], a3); a3 = dot2(wih[3][k], pi[k], a3);
    }
#pragma unroll
    for (int m = 1; m < 64; m <<= 1) {
      a0 += __shfl_xor(a0, m, 64);
      a1 += __shfl_xor(a1, m, 64);
      a2 += __shfl_xor(a2, m, 64);
      a3 += __shfl_xor(a3, m, 64);
    }
    if (lane == 0) {
      partial[wid][0] = a0; partial[wid][1] = a1;
      partial[wid][2] = a2; partial[wid][3] = a3;
    }
    __syncthreads();   // barrier2: partials ready
    if (tid < 16) {
      int bnd = tid >> 2, r = tid & 3;
      float s = partial[bnd * 2][r] + partial[bnd * 2 + 1][r] + fbias;
      st_a4(outB + (size_t)(t + 1) * HH + gb * 16 + tid, tanhf(s));
    }
    // partial[] reuse at t+1 is gated by barrier1(t+1), which wave0 reaches
    // only after its finalize store above — r2's proven ordering.
  }

  // ---- FC on h3[T-1]: layer-3 group (weight regs dead, reuse for w_fc) ----
  if (l == 3) {
    float wf[4][16];
#pragma unroll
    for (int r = 0; r < 4; ++r) {
      const float* pf = w_fc + (size_t)(rowbase + r) * HH;
#pragma unroll
      for (int k = 0; k < 8; ++k) {
        int c = half * 1024 + k * 128 + lane * 2;
        float2 a = *(const float2*)(pf + c);
        wf[r][2 * k] = a.x; wf[r][2 * k + 1] = a.y;
      }
    }
    const float* ph3 = outB + (size_t)TT * HH + sl;
    u64 o0, o1;
    for (;;) {
      o0 = ld_a8(ph3);
      o1 = ld_a8(ph3 + 2);
      if (__all(fresh8(o0) & fresh8(o1))) break;
      __builtin_amdgcn_s_sleep(2);
    }
    *(u64*)(hex_own + sl)     = o0;
    *(u64*)(hex_own + sl + 2) = o1;
    __syncthreads();

    float hv[16];
#pragma unroll
    for (int k = 0; k < 8; ++k) {
      int c = half * 1024 + k * 128 + lane * 2;
      float2 v = *(const float2*)(hex_own + c);
      hv[2 * k] = v.x; hv[2 * k + 1] = v.y;
    }
    float a0 = 0.f, a1 = 0.f, a2 = 0.f, a3 = 0.f;
#pragma unroll
    for (int k = 0; k < 16; ++k) {
      a0 += wf[0][k] * hv[k];
      a1 += wf[1][k] * hv[k];
      a2 += wf[2][k] * hv[k];
      a3 += wf[3][k] * hv[k];
    }
#pragma unroll
    for (int m = 1; m < 64; m <<= 1) {
      a0 += __shfl_xor(a0, m, 64);
      a1 += __shfl_xor(a1, m, 64);
      a2 += __shfl_xor(a2, m, 64);
      a3 += __shfl_xor(a3, m, 64);
    }
    if (lane == 0) {
      partial[wid][0] = a0; partial[wid][1] = a1;
      partial[wid][2] = a2; partial[wid][3] = a3;
    }
    __syncthreads();
    if (tid < 16) {
      int row = gb * 16 + tid;
      int bnd = tid >> 2, r = tid & 3;
      out[row] = partial[bnd * 2][r] + partial[bnd * 2 + 1][r] + b_fc[row];
    }
  }
}

extern "C" void kernel_launch(void* const* d_in, const int* in_sizes, int n_in,
                              void* d_out, int out_size, void* d_ws, size_t ws_size,
                              hipStream_t stream) {
  const float* x    = (const float*)d_in[0];
  const float* w_ih = (const float*)d_in[1];
  const float* w_hh = (const float*)d_in[2];
  const float* b_ih = (const float*)d_in[3];
  const float* b_hh = (const float*)d_in[4];
  const float* w_fc = (const float*)d_in[5];
  const float* b_fc = (const float*)d_in[6];
  float* out = (float*)d_out;
  float* ws  = (float*)d_ws;

  // 4 exchange buffers (one per layer): (TT+1) x HH floats each.
  // Sentinel-fill, then zero slot 0 (= h_{-1}) of each.
  const size_t bufFloats = (size_t)(TT + 1) * HH;
  hipMemsetAsync(ws, 0xFF, 4 * bufFloats * sizeof(float), stream);
  for (int l = 0; l < 4; ++l)
    hipMemsetAsync(ws + l * bufFloats, 0, HH * sizeof(float), stream);

  rnn_d4h<<<NBLK, NTH, 0, stream>>>(x, w_ih, w_hh, b_ih, b_hh,
                                    w_fc, b_fc, out, ws);
}